// Round 1
// baseline (112.270 us; speedup 1.0000x reference)
//
#include <hip/hip_runtime.h>
#include <hip/hip_bf16.h>
#include <stdint.h>

#define IN_F  4096
#define OUT_F 11008
#define MTOT  512

#define BM 128
#define BN 128
#define BK 64
#define NKT (IN_F / BK)   // 64 K-tiles

typedef __attribute__((ext_vector_type(4))) float  f32x4;
typedef __attribute__((ext_vector_type(4))) int    i32x4;
typedef __attribute__((ext_vector_type(2))) unsigned u32x2;
typedef __attribute__((ext_vector_type(8))) __bf16 bf16x8;

// Pack two f32 -> two bf16 (round-to-nearest via +0x8000; exact for small ints)
__device__ __forceinline__ unsigned pack2bf16(float lo, float hi) {
    unsigned ulo = __builtin_bit_cast(unsigned, lo) + 0x8000u;
    unsigned uhi = __builtin_bit_cast(unsigned, hi) + 0x8000u;
    // dst = { hi16(uhi) : hi16(ulo) }  (byte sel: uhi[3],uhi[2],ulo[3],ulo[2])
    return __builtin_amdgcn_perm(uhi, ulo, 0x07060302u);
}

__global__ __launch_bounds__(256, 2)
void qgemm_kernel(const float* __restrict__ X,      // [512][4096] fp32
                  const int*   __restrict__ W,      // [11008][4096] int32 in [-127,127]
                  const float* __restrict__ scale,  // [11008]
                  const float* __restrict__ bias,   // [11008]
                  float* __restrict__ Out)          // [512][11008] fp32
{
    // LDS: A tile [BM][BK] bf16 + B tile [BN][BK] bf16, XOR-swizzled rows.
    __shared__ __align__(16) char smem[2 * BM * BK * 2];  // 32 KiB
    char* lA = smem;
    char* lB = smem + BM * BK * 2;

    const int tid  = (int)threadIdx.x;
    const int lane = tid & 63;
    const int wid  = tid >> 6;
    const int wr   = wid >> 1;   // wave row (0..1) -> 64 output rows
    const int wc   = wid & 1;    // wave col (0..1) -> 64 output cols

    // XCD-aware bijective swizzle: grid = 344 = 8 * 43 (exact), so the 4
    // M-tiles sharing one B-panel land consecutively on the same XCD.
    const int nwg = (int)gridDim.x;
    const int bid = (int)blockIdx.x;
    const int lbid = (bid & 7) * (nwg >> 3) + (bid >> 3);
    const int mtile = lbid & 3;        // M/BM = 4
    const int ntile = lbid >> 2;       // N/BN = 86
    const int brow = mtile * BM;
    const int bcol = ntile * BN;

    // Staging map: step j in 0..7 stages row (j*16 + srow), 16B chunk scol4.
    const int srow  = tid >> 4;        // 0..15
    const int scol4 = tid & 15;        // float4 index within BK=64 cols

    const float* Xp = X + (size_t)(brow + srow) * IN_F + scol4 * 4;
    const int*   Wp = W + (size_t)(bcol + srow) * IN_F + scol4 * 4;

    f32x4 ra[8];
    i32x4 rb[8];
    f32x4 acc[4][4];
    #pragma unroll
    for (int i = 0; i < 4; ++i)
        #pragma unroll
        for (int j = 0; j < 4; ++j)
            acc[i][j] = (f32x4){0.f, 0.f, 0.f, 0.f};

    // Prologue: issue loads for K-tile 0
    #pragma unroll
    for (int j = 0; j < 8; ++j) {
        ra[j] = *(const f32x4*)(Xp + (size_t)(j * 16) * IN_F);
        rb[j] = *(const i32x4*)(Wp + (size_t)(j * 16) * IN_F);
    }

    for (int kt = 0; kt < NKT; ++kt) {
        // --- convert + ds_write (single buffer; safe under 2-barrier loop) ---
        #pragma unroll
        for (int j = 0; j < 8; ++j) {
            const int row = j * 16 + srow;
            const int off = (row * (BK * 2) + scol4 * 8) ^ ((row & 7) << 4);
            u32x2 av, bv;
            av.x = pack2bf16(ra[j].x, ra[j].y);
            av.y = pack2bf16(ra[j].z, ra[j].w);
            bv.x = pack2bf16((float)rb[j].x, (float)rb[j].y);
            bv.y = pack2bf16((float)rb[j].z, (float)rb[j].w);
            *(u32x2*)(lA + off) = av;
            *(u32x2*)(lB + off) = bv;
        }
        __syncthreads();

        // --- issue next tile's global loads (overlap with MFMA below) ---
        if (kt + 1 < NKT) {
            const float* Xk = Xp + (size_t)(kt + 1) * BK;
            const int*   Wk = Wp + (size_t)(kt + 1) * BK;
            #pragma unroll
            for (int j = 0; j < 8; ++j) {
                ra[j] = *(const f32x4*)(Xk + (size_t)(j * 16) * IN_F);
                rb[j] = *(const i32x4*)(Wk + (size_t)(j * 16) * IN_F);
            }
        }

        // --- compute: 2 K-steps of 16x16x32, 4x4 fragments per wave ---
        #pragma unroll
        for (int ks = 0; ks < 2; ++ks) {
            bf16x8 af[4], bfr[4];
            #pragma unroll
            for (int mi = 0; mi < 4; ++mi) {
                const int row = wr * 64 + mi * 16 + (lane & 15);
                const int off = (row * (BK * 2) + ks * 64 + (lane >> 4) * 16)
                                ^ ((row & 7) << 4);
                af[mi] = *(const bf16x8*)(lA + off);
            }
            #pragma unroll
            for (int ni = 0; ni < 4; ++ni) {
                const int row = wc * 64 + ni * 16 + (lane & 15);
                const int off = (row * (BK * 2) + ks * 64 + (lane >> 4) * 16)
                                ^ ((row & 7) << 4);
                bfr[ni] = *(const bf16x8*)(lB + off);
            }
            #pragma unroll
            for (int mi = 0; mi < 4; ++mi)
                #pragma unroll
                for (int ni = 0; ni < 4; ++ni)
                    acc[mi][ni] = __builtin_amdgcn_mfma_f32_16x16x32_bf16(
                        af[mi], bfr[ni], acc[mi][ni], 0, 0, 0);
        }
        __syncthreads();
    }

    // --- epilogue: out = acc / scale[col] + bias[col] ---
    // C/D mapping (verified m89/m91): col = lane&15, row = (lane>>4)*4 + j
    #pragma unroll
    for (int ni = 0; ni < 4; ++ni) {
        const int col = bcol + wc * 64 + ni * 16 + (lane & 15);
        const float inv = 1.0f / scale[col];
        const float bs  = bias[col];
        #pragma unroll
        for (int mi = 0; mi < 4; ++mi) {
            const int row0 = brow + wr * 64 + mi * 16 + ((lane >> 4) << 2);
            #pragma unroll
            for (int j = 0; j < 4; ++j) {
                Out[(size_t)(row0 + j) * OUT_F + col] = acc[mi][ni][j] * inv + bs;
            }
        }
    }
}

extern "C" void kernel_launch(void* const* d_in, const int* in_sizes, int n_in,
                              void* d_out, int out_size, void* d_ws, size_t ws_size,
                              hipStream_t stream) {
    const float* X     = (const float*)d_in[0];
    const int*   W     = (const int*)d_in[1];
    const float* scale = (const float*)d_in[2];
    const float* bias  = (const float*)d_in[3];
    float* Out = (float*)d_out;

    const int grid = (MTOT / BM) * (OUT_F / BN);  // 4 * 86 = 344
    qgemm_kernel<<<grid, 256, 0, stream>>>(X, W, scale, bias, Out);
}

// Round 2
// 107.270 us; speedup vs baseline: 1.0466x; 1.0466x over previous
//
#include <hip/hip_runtime.h>
#include <hip/hip_bf16.h>
#include <stdint.h>

#define IN_F  4096
#define OUT_F 11008
#define MTOT  512

#define BM 128
#define BN 64
#define BK 64
#define NKT (IN_F / BK)   // 64 K-tiles

typedef __attribute__((ext_vector_type(4))) float  f32x4;
typedef __attribute__((ext_vector_type(4))) int    i32x4;
typedef __attribute__((ext_vector_type(2))) unsigned u32x2;
typedef __attribute__((ext_vector_type(8))) __bf16 bf16x8;

// Pack two f32 -> two bf16 (round-to-nearest-ish via +0x8000; ints are exact)
__device__ __forceinline__ unsigned pack2bf16(float lo, float hi) {
    unsigned ulo = __builtin_bit_cast(unsigned, lo) + 0x8000u;
    unsigned uhi = __builtin_bit_cast(unsigned, hi) + 0x8000u;
    return __builtin_amdgcn_perm(uhi, ulo, 0x07060302u);
}

__global__ __launch_bounds__(256, 4)
void qgemm_kernel(const float* __restrict__ X,      // [512][4096] fp32
                  const int*   __restrict__ W,      // [11008][4096] int32 in [-127,127]
                  const float* __restrict__ scale,  // [11008]
                  const float* __restrict__ bias,   // [11008]
                  float* __restrict__ Out)          // [512][11008] fp32
{
    // LDS: A tile [BM][BK] bf16 (16 KB) + B tile [BN][BK] bf16 (8 KB), XOR-swizzled.
    __shared__ __align__(16) char smem[(BM + BN) * BK * 2];  // 24 KiB
    char* lA = smem;
    char* lB = smem + BM * BK * 2;

    const int tid  = (int)threadIdx.x;
    const int lane = tid & 63;
    const int wid  = tid >> 6;
    const int wr   = wid >> 1;   // wave row (0..1) -> 64 output rows
    const int wc   = wid & 1;    // wave col (0..1) -> 32 output cols

    // XCD-aware bijective swizzle: grid = 688 = 8 * 86 exact. Within one XCD
    // the 4 M-tiles of each B-panel (64 rows x 16 KB = 1 MB) are consecutive,
    // so 3 of 4 re-reads of W hit that XCD's L2.
    const int nwg = (int)gridDim.x;
    const int bid = (int)blockIdx.x;
    const int lbid = (bid & 7) * (nwg >> 3) + (bid >> 3);
    const int mtile = lbid & 3;        // M/BM = 4
    const int ntile = lbid >> 2;       // N/BN = 172
    const int brow = mtile * BM;
    const int bcol = ntile * BN;

    // Staging map: thread -> (srow = tid>>4 in 0..15, scol4 = tid&15 float4 chunk)
    const int srow  = tid >> 4;
    const int scol4 = tid & 15;

    const float* Xp = X + (size_t)(brow + srow) * IN_F + scol4 * 4;
    const int*   Wp = W + (size_t)(bcol + srow) * IN_F + scol4 * 4;

    f32x4 ra[8];   // A: 8 x 16 rows
    i32x4 rb[4];   // B: 4 x 16 rows
    f32x4 acc[4][2];
    #pragma unroll
    for (int i = 0; i < 4; ++i)
        #pragma unroll
        for (int j = 0; j < 2; ++j)
            acc[i][j] = (f32x4){0.f, 0.f, 0.f, 0.f};

    // Prologue: issue loads for K-tile 0
    #pragma unroll
    for (int j = 0; j < 8; ++j)
        ra[j] = *(const f32x4*)(Xp + (size_t)(j * 16) * IN_F);
    #pragma unroll
    for (int j = 0; j < 4; ++j)
        rb[j] = *(const i32x4*)(Wp + (size_t)(j * 16) * IN_F);

    for (int kt = 0; kt < NKT; ++kt) {
        // --- convert + ds_write (single buffer; 2-barrier loop) ---
        #pragma unroll
        for (int j = 0; j < 8; ++j) {
            const int row = j * 16 + srow;
            const int off = (row * (BK * 2) + scol4 * 8) ^ ((row & 7) << 4);
            u32x2 av;
            av.x = pack2bf16(ra[j].x, ra[j].y);
            av.y = pack2bf16(ra[j].z, ra[j].w);
            *(u32x2*)(lA + off) = av;
        }
        #pragma unroll
        for (int j = 0; j < 4; ++j) {
            const int row = j * 16 + srow;
            const int off = (row * (BK * 2) + scol4 * 8) ^ ((row & 7) << 4);
            u32x2 bv;
            bv.x = pack2bf16((float)rb[j].x, (float)rb[j].y);
            bv.y = pack2bf16((float)rb[j].z, (float)rb[j].w);
            *(u32x2*)(lB + off) = bv;
        }
        __syncthreads();

        // --- issue next tile's global loads (in flight across the MFMA phase) ---
        if (kt + 1 < NKT) {
            const float* Xk = Xp + (size_t)(kt + 1) * BK;
            const int*   Wk = Wp + (size_t)(kt + 1) * BK;
            #pragma unroll
            for (int j = 0; j < 8; ++j)
                ra[j] = *(const f32x4*)(Xk + (size_t)(j * 16) * IN_F);
            #pragma unroll
            for (int j = 0; j < 4; ++j)
                rb[j] = *(const i32x4*)(Wk + (size_t)(j * 16) * IN_F);
        }

        // --- compute: 2 K-steps of 16x16x32, 4x2 fragments per wave ---
        #pragma unroll
        for (int ks = 0; ks < 2; ++ks) {
            bf16x8 af[4], bfr[2];
            #pragma unroll
            for (int mi = 0; mi < 4; ++mi) {
                const int row = wr * 64 + mi * 16 + (lane & 15);
                const int off = (row * (BK * 2) + ks * 64 + (lane >> 4) * 16)
                                ^ ((row & 7) << 4);
                af[mi] = *(const bf16x8*)(lA + off);
            }
            #pragma unroll
            for (int ni = 0; ni < 2; ++ni) {
                const int row = wc * 32 + ni * 16 + (lane & 15);
                const int off = (row * (BK * 2) + ks * 64 + (lane >> 4) * 16)
                                ^ ((row & 7) << 4);
                bfr[ni] = *(const bf16x8*)(lB + off);
            }
            #pragma unroll
            for (int mi = 0; mi < 4; ++mi)
                #pragma unroll
                for (int ni = 0; ni < 2; ++ni)
                    acc[mi][ni] = __builtin_amdgcn_mfma_f32_16x16x32_bf16(
                        af[mi], bfr[ni], acc[mi][ni], 0, 0, 0);
        }
        __syncthreads();
    }

    // --- epilogue: out = acc / scale[col] + bias[col] ---
    // C/D mapping: col = lane&15, row = (lane>>4)*4 + j
    #pragma unroll
    for (int ni = 0; ni < 2; ++ni) {
        const int col = bcol + wc * 32 + ni * 16 + (lane & 15);
        const float inv = 1.0f / scale[col];
        const float bs  = bias[col];
        #pragma unroll
        for (int mi = 0; mi < 4; ++mi) {
            const int row0 = brow + wr * 64 + mi * 16 + ((lane >> 4) << 2);
            #pragma unroll
            for (int j = 0; j < 4; ++j) {
                Out[(size_t)(row0 + j) * OUT_F + col] = acc[mi][ni][j] * inv + bs;
            }
        }
    }
}

extern "C" void kernel_launch(void* const* d_in, const int* in_sizes, int n_in,
                              void* d_out, int out_size, void* d_ws, size_t ws_size,
                              hipStream_t stream) {
    const float* X     = (const float*)d_in[0];
    const int*   W     = (const int*)d_in[1];
    const float* scale = (const float*)d_in[2];
    const float* bias  = (const float*)d_in[3];
    float* Out = (float*)d_out;

    const int grid = (MTOT / BM) * (OUT_F / BN);  // 4 * 172 = 688
    qgemm_kernel<<<grid, 256, 0, stream>>>(X, W, scale, bias, Out);
}